// Round 9
// baseline (676.385 us; speedup 1.0000x reference)
//
#include <hip/hip_runtime.h>
#include <stdint.h>

// N=8192 samples, D=4096 statevector dim (fixed by reference)
#define NN 8192
#define DD 4096
#define BK 64           // K-step (one i8 MFMA covers K=64)
#define NT (DD / BK)    // 64 K-steps
#define BM 64           // tile rows (A)
#define BN 128          // tile cols (B)
#define LDS_A 8192      // 64 rows x 128 B (re[64]|im[64] i8, 8-slot XOR swizzle)
#define LDS_B 16384     // 128 rows x 128 B
#define LDSBUF (LDS_A + LDS_B)  // 24 KB
#define NTILE 4160      // staircase: sum_{bj=0}^{63} (2bj+2) = 64*65

typedef int   i32x4 __attribute__((ext_vector_type(4)));
typedef float f32x4 __attribute__((ext_vector_type(4)));

#define GLOAD(g, l) __builtin_amdgcn_global_load_lds( \
    (__attribute__((address_space(1))) uint32_t*)(void*)(size_t)(g), \
    (__attribute__((address_space(3))) uint32_t*)(void*)(l), 16, 0, 0)

#define VMW4() asm volatile("s_waitcnt vmcnt(4)" ::: "memory")
#define VMW2() asm volatile("s_waitcnt vmcnt(2)" ::: "memory")
#define VMW0() asm volatile("s_waitcnt vmcnt(0)" ::: "memory")
#define LGK0() asm volatile("s_waitcnt lgkmcnt(0)" ::: "memory")
#define SBAR() __builtin_amdgcn_s_barrier()
#define SCHED0() __builtin_amdgcn_sched_barrier(0)

#define MFMA_I8(a, b, c) __builtin_amdgcn_mfma_i32_16x16x64_i8((a), (b), (c), 0, 0, 0)

// fp32 -> per-row-scaled int8. One block per row; row in registers, block-max
// reduce, quantize, packed stores.
__global__ __launch_bounds__(256) void convert_kernel(
    const float* __restrict__ re, const float* __restrict__ im,
    char* __restrict__ re8, char* __restrict__ im8, float* __restrict__ scales) {
  __shared__ float red[4];
  const int row = blockIdx.x;
  const int t = threadIdx.x;
  const float4* rr = (const float4*)(re + (size_t)row * DD);
  const float4* ir = (const float4*)(im + (size_t)row * DD);
  float4 rv[4], iv[4];
  float mx = 0.f;
#pragma unroll
  for (int c = 0; c < 4; ++c) {
    rv[c] = rr[t * 4 + c];
    iv[c] = ir[t * 4 + c];
    mx = fmaxf(mx, fmaxf(fmaxf(fabsf(rv[c].x), fabsf(rv[c].y)),
                         fmaxf(fabsf(rv[c].z), fabsf(rv[c].w))));
    mx = fmaxf(mx, fmaxf(fmaxf(fabsf(iv[c].x), fabsf(iv[c].y)),
                         fmaxf(fabsf(iv[c].z), fabsf(iv[c].w))));
  }
#pragma unroll
  for (int off = 32; off > 0; off >>= 1) mx = fmaxf(mx, __shfl_down(mx, off));
  if ((t & 63) == 0) red[t >> 6] = mx;
  __syncthreads();
  mx = fmaxf(fmaxf(red[0], red[1]), fmaxf(red[2], red[3]));
  const float inv = (mx > 1e-30f) ? (127.0f / mx) : 0.0f;
  if (t == 0) scales[row] = mx * (1.0f / 127.0f);

  i32x4 rp, ip;
#pragma unroll
  for (int c = 0; c < 4; ++c) {
    int b0 = (int)rintf(rv[c].x * inv), b1 = (int)rintf(rv[c].y * inv);
    int b2 = (int)rintf(rv[c].z * inv), b3 = (int)rintf(rv[c].w * inv);
    rp[c] = (b0 & 0xFF) | ((b1 & 0xFF) << 8) | ((b2 & 0xFF) << 16) | (b3 << 24);
    b0 = (int)rintf(iv[c].x * inv); b1 = (int)rintf(iv[c].y * inv);
    b2 = (int)rintf(iv[c].z * inv); b3 = (int)rintf(iv[c].w * inv);
    ip[c] = (b0 & 0xFF) | ((b1 & 0xFF) << 8) | ((b2 & 0xFF) << 16) | (b3 << 24);
  }
  ((i32x4*)(re8 + (size_t)row * DD))[t] = rp;
  ((i32x4*)(im8 + (size_t)row * DD))[t] = ip;
}

// 64x128 tile of G per (bi, bj), bi <= 2bj+1 staircase (covers upper triangle).
// int8 MFMA; acc_g = re.re'+im.im', x = im.re', y = re.im'; fid = (g*s)^2+((x-y)*s)^2.
// ROUND 9: m201-style 4-phase K-step with counted vmcnt (never 0 in loop):
//  ph0: read A+B0 | GLOAD A(s+1)      | bar lgk 8MFMA bar
//  ph1: read B1   | GLOAD B01(s+1)    | vmcnt(4) bar lgk 8MFMA bar   (publishes B23(s))
//  ph2: read B2   | GLOAD B23(s+1)    | bar lgk 8MFMA bar
//  ph3: read B3   |                   | vmcnt(2) bar lgk 8MFMA bar   (publishes A,B01(s+1))
// Every load consumed 4 phases (~1400 cy) after issue. 3 blocks/CU.
__global__ __launch_bounds__(256, 3) void gram_kernel(
    const char* __restrict__ re8, const char* __restrict__ im8,
    const float* __restrict__ scales,
    float* __restrict__ wts, float* __restrict__ fidp) {
  __shared__ alignas(16) char lds[2 * LDSBUF];  // 48 KB

  // XCD-aware bijective swizzle (4160 = 8*520)
  const int b = blockIdx.x;
  const int t = (b & 7) * 520 + (b >> 3);

  // staircase: C(bj) = bj*(bj+1); bj s.t. C(bj) <= t < C(bj+1); bi = t - C(bj)
  int bj = (int)((sqrtf((float)(4 * t + 1)) - 1.0f) * 0.5f);
  if (bj < 0) bj = 0;
  if (bj > 63) bj = 63;
  while (bj > 0 && t < bj * (bj + 1)) --bj;
  while (t >= (bj + 1) * (bj + 2)) ++bj;
  const int bi = t - bj * (bj + 1);

  const int brow = bi * BM, bcol = bj * BN;
  const int tid = threadIdx.x;
  const int lane = tid & 63;
  const int wid = tid >> 6;               // 4 waves
  const int wr = wid >> 1, wc = wid & 1;  // wave-tile 32 rows x 64 cols
  const int t16 = tid * 16;

  // ---- staging source (pre-swizzled; LDS dest linear) ----
  // LDS row r (128 B): physical 16B slot p holds logical slot p ^ (r&7);
  // logical slots 0-3 = re k-chunks (16 i8 each), 4-7 = im.
  const int srow = tid >> 3;                    // 0..31
  const int slog = (tid & 7) ^ (srow & 7);
  const char* smat = (slog < 4) ? re8 : im8;
  const int scol = (slog & 3) * 16;
  const char* spA = smat + (size_t)(brow + srow) * DD + scol;
  const char* spB = smat + (size_t)(bcol + srow) * DD + scol;
  const size_t r32 = (size_t)32 * DD;

#define STAGE_A(s, bf) do { const size_t ko = (size_t)(s) * BK;   \
    char* lb_ = lds + (bf) * LDSBUF + t16;                        \
    GLOAD(spA + ko,       lb_);                                   \
    GLOAD(spA + ko + r32, lb_ + 4096); } while (0)
#define STAGE_B01(s, bf) do { const size_t ko = (size_t)(s) * BK; \
    char* lb_ = lds + (bf) * LDSBUF + LDS_A + t16;                \
    GLOAD(spB + ko,           lb_);                               \
    GLOAD(spB + ko + 2 * r32, lb_ + 8192); } while (0)
#define STAGE_B23(s, bf) do { const size_t ko = (size_t)(s) * BK; \
    char* lb_ = lds + (bf) * LDSBUF + LDS_A + t16;                \
    GLOAD(spB + ko + r32,     lb_ + 4096);                        \
    GLOAD(spB + ko + 3 * r32, lb_ + 12288); } while (0)

  // ---- fragment read offsets (verified: slot_phys = kg ^ (row&7)) ----
  const int fr = lane & 15;
  const int kg = lane >> 4;
  const int reslot = (kg ^ (fr & 7)) << 4;   // re frag byte slot; im = ^64
  const int arow = (wr * 32 + fr) * 128;     // + m*2048, A region @0
  const int brw  = (wc * 64 + fr) * 128;     // + n*2048, B region @LDS_A

  i32x4 acc_g[2][4], acc_x[2][4], acc_y[2][4];
#pragma unroll
  for (int m = 0; m < 2; ++m)
#pragma unroll
    for (int n = 0; n < 4; ++n) {
      acc_g[m][n] = (i32x4){0, 0, 0, 0};
      acc_x[m][n] = (i32x4){0, 0, 0, 0};
      acc_y[m][n] = (i32x4){0, 0, 0, 0};
    }

#define MFMA8(n) do {                                          \
    _Pragma("unroll") for (int m = 0; m < 2; ++m) {            \
      acc_g[m][n] = MFMA_I8(arf[m], brf, acc_g[m][n]);         \
      acc_g[m][n] = MFMA_I8(aif[m], bif, acc_g[m][n]);         \
      acc_x[m][n] = MFMA_I8(aif[m], brf, acc_x[m][n]);         \
      acc_y[m][n] = MFMA_I8(arf[m], bif, acc_y[m][n]);         \
    } } while (0)

  // ---- prologue: stage step 0 fully, one-time drain ----
  STAGE_A(0, 0); STAGE_B01(0, 0); STAGE_B23(0, 0);
  VMW0();
  SBAR();

  for (int s = 0; s < NT; ++s) {
    const char* la = lds + (s & 1) * LDSBUF;
    const char* lb = la + LDS_A;
    const int nb = (s & 1) ^ 1;
    const bool pf = (s + 1 < NT);
    i32x4 arf[2], aif[2], brf, bif;

    // ---- phase 0: A frags + B0 ; issue A(s+1) ----
#pragma unroll
    for (int m = 0; m < 2; ++m) {
      arf[m] = *(const i32x4*)(la + arow + m * 2048 + reslot);
      aif[m] = *(const i32x4*)(la + arow + m * 2048 + (reslot ^ 64));
    }
    brf = *(const i32x4*)(lb + brw + 0 * 2048 + reslot);
    bif = *(const i32x4*)(lb + brw + 0 * 2048 + (reslot ^ 64));
    if (pf) STAGE_A(s + 1, nb);
    SBAR(); LGK0(); SCHED0();
    __builtin_amdgcn_s_setprio(1);
    MFMA8(0);
    __builtin_amdgcn_s_setprio(0);
    SBAR();

    // ---- phase 1: B1 ; issue B01(s+1) ; publish B23(s) via vmcnt(4) ----
    brf = *(const i32x4*)(lb + brw + 1 * 2048 + reslot);
    bif = *(const i32x4*)(lb + brw + 1 * 2048 + (reslot ^ 64));
    if (pf) { STAGE_B01(s + 1, nb); VMW4(); } else { VMW0(); }
    SBAR(); LGK0(); SCHED0();
    __builtin_amdgcn_s_setprio(1);
    MFMA8(1);
    __builtin_amdgcn_s_setprio(0);
    SBAR();

    // ---- phase 2: B2 ; issue B23(s+1) ----
    brf = *(const i32x4*)(lb + brw + 2 * 2048 + reslot);
    bif = *(const i32x4*)(lb + brw + 2 * 2048 + (reslot ^ 64));
    if (pf) STAGE_B23(s + 1, nb);
    SBAR(); LGK0(); SCHED0();
    __builtin_amdgcn_s_setprio(1);
    MFMA8(2);
    __builtin_amdgcn_s_setprio(0);
    SBAR();

    // ---- phase 3: B3 ; publish A+B01(s+1) via vmcnt(2); B23(s+1) stays in flight ----
    brf = *(const i32x4*)(lb + brw + 3 * 2048 + reslot);
    bif = *(const i32x4*)(lb + brw + 3 * 2048 + (reslot ^ 64));
    if (pf) VMW2();
    SBAR(); LGK0(); SCHED0();
    __builtin_amdgcn_s_setprio(1);
    MFMA8(3);
    __builtin_amdgcn_s_setprio(0);
    SBAR();
  }

  // ---- epilogue: 16x16 C/D layout (verified): col=lane&15, row=(lane>>4)*4+reg ----
  const int grow0 = brow + wr * 32 + kg * 4;  // + m*16 + j
  const int gcol0 = bcol + wc * 64 + fr;      // + n*16
  const bool fullUpper = (brow + BM) <= bcol; // tile entirely strictly-upper
  const f32x4 zz = {0.f, 0.f, 0.f, 0.f};

#pragma unroll
  for (int m = 0; m < 2; ++m) {
#pragma unroll
    for (int n = 0; n < 4; ++n) {
      const int gc = gcol0 + n * 16;
      const float sb = scales[gc];
      f32x4 fv;
#pragma unroll
      for (int j = 0; j < 4; ++j) {
        const int grow = grow0 + m * 16 + j;
        const float ss = scales[grow] * sb;
        const float gr = (float)acc_g[m][n][j] * ss;
        const float gi = (float)(acc_x[m][n][j] - acc_y[m][n][j]) * ss;
        fv[j] = gr * gr + gi * gi;
      }
#pragma unroll
      for (int j = 0; j < 4; ++j) {
        const int grow = grow0 + m * 16 + j;
        const float f = fv[j];
        fidp[(size_t)grow * NN + gc] = f;
        float w = 0.0f;
        if (grow < gc) w = (f >= 0.8f) ? 1.0f : ((f >= 0.5f) ? 0.5f : 0.0f);
        wts[(size_t)grow * NN + gc] = w;
      }
      // mirror: fid symmetric; mirror targets are strictly-lower -> wts = 0
      if (fullUpper) {
        *(f32x4*)(fidp + (size_t)gc * NN + grow0 + m * 16) = fv;
        *(f32x4*)(wts  + (size_t)gc * NN + grow0 + m * 16) = zz;
      } else {
#pragma unroll
        for (int j = 0; j < 4; ++j) {
          const int grow = grow0 + m * 16 + j;
          if (grow < gc) {
            fidp[(size_t)gc * NN + grow] = fv[j];
            wts[(size_t)gc * NN + grow] = 0.0f;
          }
        }
      }
    }
  }
}

extern "C" void kernel_launch(void* const* d_in, const int* in_sizes, int n_in,
                              void* d_out, int out_size, void* d_ws, size_t ws_size,
                              hipStream_t stream) {
  const float* re = (const float*)d_in[0];
  const float* im = (const float*)d_in[1];
  float* out = (float*)d_out;

  char* re8 = (char*)d_ws;                               // N*D i8
  char* im8 = re8 + (size_t)NN * DD;                     // N*D i8
  float* scales = (float*)(im8 + (size_t)NN * DD);       // N f32  (~67 MB total)

  convert_kernel<<<NN, 256, 0, stream>>>(re, im, re8, im8, scales);
  gram_kernel<<<NTILE, 256, 0, stream>>>(re8, im8, scales, out, out + (size_t)NN * NN);
}